// Round 2
// baseline (74.357 us; speedup 1.0000x reference)
//
#include <hip/hip_runtime.h>

// ROI head matcher. R6: amortization/ILP restructure (M=2 proposals/lane).
// R5 post-mortem: swapping the in-loop GT fetch from LDS broadcast to
// s_load was NEUTRAL (72.5 -> 73.5, the +1us being the extra prep launch).
// So the fetch path is not the bottleneck; the ~4x gap over the ~7us
// VALU-issue floor must be per-wave fixed cost + latency exposure across
// 12.5k very short waves (32 iters each).
//
// R6: each lane owns TWO proposals (p0 = base+lane, p1 = base+64+lane).
// Block 256 covers 128 proposals; wave w scans GTs [32w,32w+32) as in R4.
//  - wave count halves (6252, ~6/SIMD), per-wave fixed cost amortized 2x
//  - GT record fetch + loop overhead amortized over 2 pairs
//  - the two Dekker compare chains are independent -> 2x ILP on the
//    loop-carried dependency
//  - partials stored struct-of-arrays (4B stride, bank-conflict-free,
//    vs the 8-way-conflicting float4 pattern)
//  - back to a single launch (prep folded into block staging, as in R4)
//
// Math identical to R4/R5 (validated absmax 0): exact Dekker cross-product
// argmax compare  inter_g/uni_g > inter_b/uni_b  <=>  (p1+e1) > (p2+e2),
// e = fmaf(a,b,-p); strict '>' in ascending-g order preserves first-index
// semantics; sentinel (0,1,g0) is an in-range iou-0 candidate so all-zero
// rows resolve to g=0 like jnp.argmax. One IEEE divide in the epilogue
// reproduces best_match_iou bit-exactly.

#define BLOCK 256
#define PPB 128             // proposals per block (64 lanes x 2)
#define GT_TOTAL 128
#define GT_PER_WAVE 32
#define IOU_THRESHOLD 0.5f
#define LOW_BG_IOU 0.1f

__global__ __launch_bounds__(BLOCK) void roi_match_kernel(
    const float* __restrict__ proposals,   // [N,4]
    const float* __restrict__ gt_boxes,    // [G,4]
    const int*   __restrict__ gt_labels,   // [G]
    float* __restrict__ out,               // [N] labels then [N,4] boxes
    int N)
{
#pragma clang fp contract(off)
    __shared__ float s_rec[GT_TOTAL][8];    // x1,y1,x2,y2,area,label,pad,pad
    __shared__ float s_pin[4][2][64];       // partial inter  [wave][slot][lane]
    __shared__ float s_pun[4][2][64];       // partial union
    __shared__ float s_pbi[4][2][64];       // partial argmax (bits)

    int tid = threadIdx.x;
    if (tid < GT_TOTAL) {
        float4 b = ((const float4*)gt_boxes)[tid];
        s_rec[tid][0] = b.x; s_rec[tid][1] = b.y;
        s_rec[tid][2] = b.z; s_rec[tid][3] = b.w;
        s_rec[tid][4] = (b.z - b.x) * (b.w - b.y);   // area, rounded like ref
        s_rec[tid][5] = (float)gt_labels[tid];
        s_rec[tid][6] = 0.0f; s_rec[tid][7] = 0.0f;
    }
    __syncthreads();

    int wave = tid >> 6;
    int lane = tid & 63;
    int base = blockIdx.x * PPB;
    int n0 = base + lane;                   // always < N (N % 64 == 0)
    int n1 = base + 64 + lane;
    int n0c = n0 < N ? n0 : N - 1;          // clamp loads; stores guarded
    int n1c = n1 < N ? n1 : N - 1;

    float4 P0 = ((const float4*)proposals)[n0c];
    float4 P1 = ((const float4*)proposals)[n1c];
    float a0 = (P0.z - P0.x) * (P0.w - P0.y);
    float a1 = (P1.z - P1.x) * (P1.w - P1.y);

    int g0 = wave * GT_PER_WAVE;
    int   bi0 = g0,   bi1 = g0;             // sentinel: iou 0 at first g
    float in0 = 0.0f, un0 = 1.0f;
    float in1 = 0.0f, un1 = 1.0f;

#pragma unroll 4
    for (int j = 0; j < GT_PER_WAVE; ++j) {
        int g = g0 + j;                     // wave-uniform -> LDS broadcast
        float4 gb   = *(const float4*)&s_rec[g][0];
        float garea = s_rec[g][4];

        // ---- pair 0 (independent chain) ----
        {
            float x1 = fmaxf(gb.x, P0.x);
            float y1 = fmaxf(gb.y, P0.y);
            float x2 = fminf(gb.z, P0.z);
            float y2 = fminf(gb.w, P0.w);
            float iw = fmaxf(x2 - x1, 0.0f);
            float ih = fmaxf(y2 - y1, 0.0f);
            float inter = iw * ih;
            float uni   = (garea + a0) - inter;

            float p1 = inter * un0;
            float e1 = fmaf(inter, un0, -p1);
            float p2 = in0 * uni;
            float e2 = fmaf(in0, uni, -p2);
            bool gt = (p1 - p2) > (e2 - e1);    // exact P1 > P2

            bi0 = gt ? g     : bi0;
            in0 = gt ? inter : in0;
            un0 = gt ? uni   : un0;
        }
        // ---- pair 1 (independent chain) ----
        {
            float x1 = fmaxf(gb.x, P1.x);
            float y1 = fmaxf(gb.y, P1.y);
            float x2 = fminf(gb.z, P1.z);
            float y2 = fminf(gb.w, P1.w);
            float iw = fmaxf(x2 - x1, 0.0f);
            float ih = fmaxf(y2 - y1, 0.0f);
            float inter = iw * ih;
            float uni   = (garea + a1) - inter;

            float p1 = inter * un1;
            float e1 = fmaf(inter, un1, -p1);
            float p2 = in1 * uni;
            float e2 = fmaf(in1, uni, -p2);
            bool gt = (p1 - p2) > (e2 - e1);

            bi1 = gt ? g     : bi1;
            in1 = gt ? inter : in1;
            un1 = gt ? uni   : un1;
        }
    }

    s_pin[wave][0][lane] = in0;
    s_pun[wave][0][lane] = un0;
    s_pbi[wave][0][lane] = __int_as_float(bi0);
    s_pin[wave][1][lane] = in1;
    s_pun[wave][1][lane] = un1;
    s_pbi[wave][1][lane] = __int_as_float(bi1);
    __syncthreads();

    if (wave < 2) {                         // wave = output slot
        int slot = wave;
        int n = base + slot * 64 + lane;
        if (n < N) {
            float binter = s_pin[0][slot][lane];
            float buni   = s_pun[0][slot][lane];
            int   bbi    = __float_as_int(s_pbi[0][slot][lane]);
#pragma unroll
            for (int w = 1; w < 4; ++w) {   // ascending g-range order
                float ci = s_pin[w][slot][lane];
                float cu = s_pun[w][slot][lane];
                float p1 = ci * buni;
                float e1 = fmaf(ci, buni, -p1);
                float p2 = binter * cu;
                float e2 = fmaf(binter, cu, -p2);
                bool gt = (p1 - p2) > (e2 - e1);
                bbi    = gt ? __float_as_int(s_pbi[w][slot][lane]) : bbi;
                binter = gt ? ci : binter;
                buni   = gt ? cu : buni;
            }

            float best = binter / buni;     // IEEE div, matches reference max

            float lab;
            if (best < LOW_BG_IOU)          lab = -1.0f;           // ignored
            else if (best < IOU_THRESHOLD)  lab = 0.0f;            // background
            else                            lab = s_rec[bbi][5];   // gt label

            out[n] = lab;
            ((float4*)(out + N))[n] = *(const float4*)&s_rec[bbi][0];
        }
    }
}

extern "C" void kernel_launch(void* const* d_in, const int* in_sizes, int n_in,
                              void* d_out, int out_size, void* d_ws, size_t ws_size,
                              hipStream_t stream) {
    const float* proposals = (const float*)d_in[0];
    const float* gt_boxes  = (const float*)d_in[1];
    const int*   gt_labels = (const int*)d_in[2];
    float* out = (float*)d_out;

    int N = in_sizes[0] / 4;               // 200000
    int blocks = (N + PPB - 1) / PPB;      // 1563

    roi_match_kernel<<<blocks, BLOCK, 0, stream>>>(proposals, gt_boxes,
                                                   gt_labels, out, N);
}